// Round 2
// baseline (116.217 us; speedup 1.0000x reference)
//
#include <hip/hip_runtime.h>

// ProximityAwareLoss4Class — fused weighted CE + proximity decay/boost + mean.
// B=512 rows, S=8192 positions, C=4 classes. One block per row.
//
// Proximity logic: distances only matter up to TOL=5, so nearest-dist scans
// reduce to an 11-bit window over per-row bitmasks (built with wave64 ballot),
// plus one row-wide any_pred OR per class.

#define S_LEN 8192
#define NTHREADS 1024              // 16 waves/block, 2 blocks/CU -> 32 waves/CU
#define NITER (S_LEN / NTHREADS)   // 8
#define NWORDS (S_LEN / 32)        // 256 u32 words per mask
#define NWAVES (NTHREADS / 64)     // 16

// Extract bits for positions [pos-5, pos+5] (clipped to [0,S)) into low 11 bits.
__device__ inline unsigned win11(const unsigned* m, int pos) {
    int bse = pos - 5;
    int j = bse >> 5;            // arithmetic shift; j in [-1, 255]
    int off = bse & 31;
    unsigned lo = (j >= 0) ? m[j] : 0u;
    unsigned hi = (j < NWORDS - 1) ? m[j + 1] : 0u;
    unsigned long long c = (unsigned long long)lo | ((unsigned long long)hi << 32);
    return (unsigned)((c >> off) & 0x7FFull);
}

// decay * tfac factor for one switch class.
// tw  = 11-bit window of true-switch mask (bit 5 = self)
// pw  = 11-bit window of pred-switch mask (bit 5 = self)
// anyp = any predicted switch of this class anywhere in the row
__device__ inline float prox_factor(unsigned tw, unsigned pw, bool anyp) {
    bool tm = (tw >> 5) & 1u;
    bool pm = (pw >> 5) & 1u;
    float f = 1.0f;
    unsigned tn = tw & ~(1u << 5);   // true bits excluding self
    if (pm && !tm && tn) {
        // min distance d in 1..5: bit pairs (5-d, 5+d)
        if      (tn & 0x050u) f = 0.8f;      // d=1: bits 4,6
        else if (tn & 0x088u) f = 0.64f;     // d=2: bits 3,7
        else if (tn & 0x104u) f = 0.512f;    // d=3: bits 2,8
        else if (tn & 0x202u) f = 0.4096f;   // d=4: bits 1,9
        else                  f = 0.32768f;  // d=5: bits 0,10
    }
    if (tm) {
        // d_tp <= TOL  <=>  any pred bit (incl. self) in the window
        f *= anyp ? (pw ? 1.0f : 1.5f) : 2.0f;
    }
    return f;
}

__global__ __launch_bounds__(NTHREADS)
void prox_loss_main(const float* __restrict__ logits,
                    const int* __restrict__ labels,
                    const float* __restrict__ cw,
                    float* __restrict__ acc) {
    __shared__ float ce_lds[S_LEN];                  // 32 KB
    __shared__ unsigned t2m[NWORDS], t3m[NWORDS];    // 1 KB each
    __shared__ unsigned p2m[NWORDS], p3m[NWORDS];
    __shared__ unsigned anyf[2];
    __shared__ float part_s[NWAVES], part_v[NWAVES];

    const int tid = threadIdx.x;
    const int row = blockIdx.x;
    const long base = (long)row * S_LEN;

    if (tid < 2) anyf[tid] = 0u;

    const float w0 = cw[0], w1 = cw[1], w2 = cw[2], w3 = cw[3];

    float local_valid = 0.0f;

    // ---- Pass 1: CE per position + bitmask build ----
    for (int k = 0; k < NITER; ++k) {
        const int pos = k * NTHREADS + tid;
        const long g = base + pos;
        const float4 x = reinterpret_cast<const float4*>(logits)[g];
        const int lab = labels[g];

        // argmax (first max wins, matches jnp.argmax)
        int pred = 0; float best = x.x;
        if (x.y > best) { best = x.y; pred = 1; }
        if (x.z > best) { best = x.z; pred = 2; }
        if (x.w > best) { best = x.w; pred = 3; }

        // log-softmax CE
        const float m = fmaxf(fmaxf(x.x, x.y), fmaxf(x.z, x.w));
        const float s = expf(x.x - m) + expf(x.y - m) + expf(x.z - m) + expf(x.w - m);
        const float lse = m + logf(s);
        const int safe = (lab < 0) ? 0 : lab;
        const float xl = (safe == 0) ? x.x : (safe == 1) ? x.y : (safe == 2) ? x.z : x.w;
        const float ws = (safe == 0) ? w0  : (safe == 1) ? w1  : (safe == 2) ? w2  : w3;
        const float ce = (lab < 0) ? 0.0f : ws * (lse - xl);
        ce_lds[pos] = ce;
        if (lab >= 0) local_valid += 1.0f;

        // wave64 ballots -> 64 consecutive positions per wave
        const unsigned long long bt2 = __ballot(lab == 2);
        const unsigned long long bt3 = __ballot(lab == 3);
        const unsigned long long bp2 = __ballot(pred == 2);
        const unsigned long long bp3 = __ballot(pred == 3);
        if ((tid & 63) == 0) {
            const int widx = pos >> 5;   // pos is multiple of 64 here
            t2m[widx] = (unsigned)bt2; t2m[widx + 1] = (unsigned)(bt2 >> 32);
            t3m[widx] = (unsigned)bt3; t3m[widx + 1] = (unsigned)(bt3 >> 32);
            p2m[widx] = (unsigned)bp2; p2m[widx + 1] = (unsigned)(bp2 >> 32);
            p3m[widx] = (unsigned)bp3; p3m[widx + 1] = (unsigned)(bp3 >> 32);
        }
    }
    __syncthreads();

    // ---- any_pred per class (row-wide OR) ----
    if (tid < NWORDS) {
        if (p2m[tid] != 0u) atomicOr(&anyf[0], 1u);
        if (p3m[tid] != 0u) atomicOr(&anyf[1], 1u);
    }
    __syncthreads();
    const bool any2 = anyf[0] != 0u;
    const bool any3 = anyf[1] != 0u;

    // ---- Pass 2: apply proximity factors, accumulate ----
    float local_sum = 0.0f;
    for (int k = 0; k < NITER; ++k) {
        const int pos = k * NTHREADS + tid;
        float f = ce_lds[pos];
        const unsigned tw2 = win11(t2m, pos), pw2 = win11(p2m, pos);
        const unsigned tw3 = win11(t3m, pos), pw3 = win11(p3m, pos);
        f *= prox_factor(tw2, pw2, any2);
        f *= prox_factor(tw3, pw3, any3);
        local_sum += f;
    }

    // ---- block reduce (wave shuffle then LDS) ----
    for (int o = 32; o > 0; o >>= 1) {
        local_sum   += __shfl_down(local_sum, o);
        local_valid += __shfl_down(local_valid, o);
    }
    const int wv = tid >> 6;
    if ((tid & 63) == 0) { part_s[wv] = local_sum; part_v[wv] = local_valid; }
    __syncthreads();
    if (tid == 0) {
        float ssum = 0.0f, vsum = 0.0f;
        for (int i = 0; i < NWAVES; ++i) { ssum += part_s[i]; vsum += part_v[i]; }
        atomicAdd(&acc[0], ssum);
        atomicAdd(&acc[1], vsum);
    }
}

__global__ void prox_loss_finalize(const float* __restrict__ acc,
                                   float* __restrict__ out) {
    out[0] = acc[0] / fmaxf(acc[1], 1.0f);
}

extern "C" void kernel_launch(void* const* d_in, const int* in_sizes, int n_in,
                              void* d_out, int out_size, void* d_ws, size_t ws_size,
                              hipStream_t stream) {
    const float* logits = (const float*)d_in[0];
    const int*   labels = (const int*)d_in[1];
    const float* cw     = (const float*)d_in[2];
    float* out = (float*)d_out;
    float* acc = (float*)d_ws;

    const int B = in_sizes[1] / S_LEN;   // 512

    hipMemsetAsync(acc, 0, 2 * sizeof(float), stream);
    prox_loss_main<<<B, NTHREADS, 0, stream>>>(logits, labels, cw, acc);
    prox_loss_finalize<<<1, 1, 0, stream>>>(acc, out);
}